// Round 4
// baseline (33.426 us; speedup 1.0000x reference)
//
#include <hip/hip_runtime.h>

#define GRIDSZ 13
#define NANCH  5
#define NCHAN  25
#define BATCH  2048
#define NOBJ   32
#define PLANE  (GRIDSZ * GRIDSZ)        // 169

// ANCHORS / 13, folded at compile time in IEEE f32 (matches JAX runtime division)
__constant__ float AW[NANCH] = {1.3221f / 13.0f, 3.19275f / 13.0f, 5.05587f / 13.0f,
                                9.47112f / 13.0f, 11.2364f / 13.0f};
__constant__ float AH[NANCH] = {1.73145f / 13.0f, 4.00944f / 13.0f, 8.09892f / 13.0f,
                                4.84053f / 13.0f, 10.0071f / 13.0f};

// One block per batch image. 256 threads.
//  A: (gt,anchor) IoU on 160 threads (4 scattered loads each) -> LDS
//  D: baseline 0.5*d4^2 over this batch's 5 ch-4 planes (all 256 threads, pre-sync)
//  B: argmax + winner resolution on 32 threads
//  C: winner corrections (32 thr for ch0-4; 640 (gt,cls-ch) items on 256 thr)
// Block writes one float4 partial {loss, obj, noobj, conf}.
__global__ void __launch_bounds__(256) main_kernel(const float* __restrict__ det,
                                                   const float* __restrict__ gt_boxes,
                                                   const int* __restrict__ gt_class,
                                                   float4* __restrict__ partials) {
    int b = blockIdx.x;
    int t = threadIdx.x;
    __shared__ float  iou_sm[NOBJ * NANCH];   // 160
    __shared__ float4 pred_sm[NOBJ * NANCH];  // px,py,pw*AW,ph*AH
    __shared__ float4 box_sm[NOBJ];
    __shared__ int    gx_sm[NOBJ], gy_sm[NOBJ];
    __shared__ int    cls_sm[NOBJ];
    __shared__ int    flat_sm[NOBJ];
    __shared__ int    aidx_sm[NOBJ];
    __shared__ int    win_sm[NOBJ];
    __shared__ float  sm4[4][4];

    const float* detb = det + (size_t)b * (NANCH * NCHAN) * PLANE;

    float loss = 0.0f, objl = 0.0f, noobjl = 0.0f, confl = 0.0f;

    // ---- Phase A: IoU per (gt, anchor) ----
    if (t < NOBJ * NANCH) {
        int gt = t / NANCH, a = t - gt * NANCH;
        float4 g = ((const float4*)gt_boxes)[b * NOBJ + gt];
        float x = g.x, y = g.y, w = g.z, h = g.w;
        int gx = (int)floorf(x * 13.0f);
        int gy = (int)floorf(y * 13.0f);
        if (a == 0) {
            gx_sm[gt] = gx; gy_sm[gt] = gy;
            box_sm[gt] = g;
            cls_sm[gt] = gt_class[b * NOBJ + gt];
        }
        const float* p = detb + (size_t)a * NCHAN * PLANE + gy * GRIDSZ + gx;
        float px = p[0];
        float py = p[PLANE];
        float pw = p[2 * PLANE] * AW[a];
        float ph = p[3 * PLANE] * AH[a];
        float gx0 = x - w * 0.5f, gy0 = y - h * 0.5f;
        float gx1 = x + w * 0.5f, gy1 = y + h * 0.5f;
        float a1 = (gx1 - gx0 + 1.0f) * (gy1 - gy0 + 1.0f);
        float bx0 = (px + (float)gx) / 13.0f - pw * 0.5f;
        float by0 = (py + (float)gy) / 13.0f - ph * 0.5f;
        float bx1 = bx0 + pw, by1 = by0 + ph;
        float ix0 = fmaxf(gx0, bx0), iy0 = fmaxf(gy0, by0);
        float ix1 = fminf(gx1, bx1), iy1 = fminf(gy1, by1);
        float inter = (ix1 - ix0 + 1.0f) * (iy1 - iy0 + 1.0f);
        float a2 = (bx1 - bx0 + 1.0f) * (by1 - by0 + 1.0f);
        iou_sm[t] = inter / (a1 + a2 - inter);
        pred_sm[t] = make_float4(px, py, pw, ph);
    }

    // ---- Phase D: baseline (independent of LDS; overlaps A's latency) ----
    {
        float s = 0.0f;
        for (int idx = t; idx < NANCH * PLANE; idx += 256) {
            int a = idx / PLANE, i = idx - a * PLANE;
            float d = detb[((size_t)a * NCHAN + 4) * PLANE + i];
            s += d * d;
        }
        loss += 0.5f * s;
        noobjl += 0.5f * s;
    }

    __syncthreads();

    // ---- Phase B1: per-GT argmax (first-max, matches jnp.argmax) ----
    if (t < NOBJ) {
        float best = -INFINITY;
        int aidx = 0;
        #pragma unroll
        for (int a = 0; a < NANCH; ++a) {
            float v = iou_sm[t * NANCH + a];
            if (v > best) { best = v; aidx = a; }
        }
        aidx_sm[t] = aidx;
        flat_sm[t] = (aidx * GRIDSZ + gy_sm[t]) * GRIDSZ + gx_sm[t];  // batch-local slot
    }
    __syncthreads();

    // ---- Phase B2: winner = no higher-index GT in batch with same slot ----
    if (t < NOBJ) {
        int f = flat_sm[t];
        int winner = 1;
        for (int m = t + 1; m < NOBJ; ++m)
            if (flat_sm[m] == f) winner = 0;
        win_sm[t] = winner;
    }
    __syncthreads();

    // ---- Phase C1: ch0-4 terms + baseline subtraction (winners, t<32) ----
    if (t < NOBJ && win_sm[t]) {
        int aidx = aidx_sm[t];
        float4 pr = pred_sm[t * NANCH + aidx];
        float4 g = box_sm[t];
        int gx = gx_sm[t], gy = gy_sm[t];
        const float* p = detb + (size_t)aidx * NCHAN * PLANE + gy * GRIDSZ + gx;
        float d4 = p[4 * PLANE];
        float tx = g.x * 13.0f - (float)gx;
        float ty = g.y * 13.0f - (float)gy;
        float e, tt, corr = 0.0f;
        e = tx - pr.x;  tt = 5.0f * e * e; corr += tt; objl += tt;
        e = ty - pr.y;  tt = 5.0f * e * e; corr += tt; objl += tt;
        e = g.z - pr.z; tt = 5.0f * e * e; corr += tt; objl += tt;
        e = g.w - pr.w; tt = 5.0f * e * e; corr += tt; objl += tt;
        e = 1.0f - d4;  tt = e * e;        corr += tt; objl += tt;
        float sub = 0.5f * d4 * d4;   // baseline term this owned cell replaces
        loss += corr - sub;
        noobjl -= sub;
    }

    // ---- Phase C2: class-channel terms, 640 (gt, c) items over 256 threads ----
    for (int item = t; item < NOBJ * 20; item += 256) {
        int gt = item / 20;
        int c = 5 + (item - gt * 20);
        if (win_sm[gt]) {
            int aidx = aidx_sm[gt];
            float d = detb[((size_t)aidx * NCHAN + c) * PLANE + gy_sm[gt] * GRIDSZ + gx_sm[gt]];
            float gtv = (c - 5 == cls_sm[gt]) ? 1.0f : 0.0f;
            float e = gtv - d;
            float tt = e * e;
            loss += tt;
            confl += tt;
        }
    }

    // ---- block reduction -> one float4 partial ----
    #pragma unroll
    for (int off = 32; off > 0; off >>= 1) {
        loss   += __shfl_down(loss, off);
        objl   += __shfl_down(objl, off);
        noobjl += __shfl_down(noobjl, off);
        confl  += __shfl_down(confl, off);
    }
    int lane = t & 63;
    int wid  = t >> 6;
    if (lane == 0) {
        sm4[wid][0] = loss; sm4[wid][1] = objl; sm4[wid][2] = noobjl; sm4[wid][3] = confl;
    }
    __syncthreads();
    if (t == 0) {
        float s0 = 0, s1 = 0, s2 = 0, s3 = 0;
        #pragma unroll
        for (int i = 0; i < 4; ++i) {
            s0 += sm4[i][0]; s1 += sm4[i][1]; s2 += sm4[i][2]; s3 += sm4[i][3];
        }
        partials[blockIdx.x] = make_float4(s0, s1, s2, s3);
    }
}

// Final: one block sums BATCH float4 partials and writes out[0..3].
__global__ void reduce_kernel(const float4* __restrict__ partials,
                              float* __restrict__ out) {
    float s0 = 0, s1 = 0, s2 = 0, s3 = 0;
    for (int i = threadIdx.x; i < BATCH; i += 256) {
        float4 v = partials[i];
        s0 += v.x; s1 += v.y; s2 += v.z; s3 += v.w;
    }
    #pragma unroll
    for (int off = 32; off > 0; off >>= 1) {
        s0 += __shfl_down(s0, off);
        s1 += __shfl_down(s1, off);
        s2 += __shfl_down(s2, off);
        s3 += __shfl_down(s3, off);
    }
    __shared__ float sm[4][4];
    int lane = threadIdx.x & 63;
    int wid  = threadIdx.x >> 6;
    if (lane == 0) {
        sm[wid][0] = s0; sm[wid][1] = s1; sm[wid][2] = s2; sm[wid][3] = s3;
    }
    __syncthreads();
    if (threadIdx.x == 0) {
        float a0 = 0, a1 = 0, a2 = 0, a3 = 0;
        #pragma unroll
        for (int i = 0; i < 4; ++i) {
            a0 += sm[i][0]; a1 += sm[i][1]; a2 += sm[i][2]; a3 += sm[i][3];
        }
        out[0] = a0; out[1] = a1; out[2] = a2; out[3] = a3;
    }
}

extern "C" void kernel_launch(void* const* d_in, const int* in_sizes, int n_in,
                              void* d_out, int out_size, void* d_ws, size_t ws_size,
                              hipStream_t stream) {
    const float* det = (const float*)d_in[0];
    const float* gtb = (const float*)d_in[1];
    const int*   gtc = (const int*)d_in[2];
    float* out = (float*)d_out;
    float4* partials = (float4*)d_ws;   // BATCH * 16 B = 32 KB

    main_kernel<<<BATCH, 256, 0, stream>>>(det, gtb, gtc, partials);
    reduce_kernel<<<1, 256, 0, stream>>>(partials, out);
}

// Round 5
// 32.313 us; speedup vs baseline: 1.0345x; 1.0345x over previous
//
#include <hip/hip_runtime.h>

#define GRIDSZ 13
#define NANCH  5
#define NCHAN  25
#define BATCH  2048
#define NOBJ   32
#define PLANE  169                      // 13*13
#define CHUNK  (NCHAN * PLANE)          // 4225 floats per (batch,anchor)
#define STG    (NANCH * 5 * PLANE)      // 4225 floats staged: ch0-4 x 5 anchors

// ANCHORS / 13, folded at compile time in IEEE f32 (matches JAX runtime division)
__constant__ float AW[NANCH] = {1.3221f / 13.0f, 3.19275f / 13.0f, 5.05587f / 13.0f,
                                9.47112f / 13.0f, 11.2364f / 13.0f};
__constant__ float AH[NANCH] = {1.73145f / 13.0f, 4.00944f / 13.0f, 8.09892f / 13.0f,
                                4.84053f / 13.0f, 10.0071f / 13.0f};

// One block per batch image, 256 threads.
//  Stage: ch0-4 planes of all 5 anchors -> LDS (dense, coalesced; 16.9 KB)
//  A: (gt,anchor) IoU from LDS (160 threads)
//  D: baseline 0.5*d4^2 from LDS (all threads)
//  B: argmax + in-LDS winner resolution (32 threads)
//  C1: winner ch0-4 terms from LDS; C2: class channels scattered from global
// Block writes one float4 partial {loss, obj, noobj, conf}.
__global__ void __launch_bounds__(256) main_kernel(const float* __restrict__ det,
                                                   const float* __restrict__ gt_boxes,
                                                   const int* __restrict__ gt_class,
                                                   float4* __restrict__ partials) {
    int b = blockIdx.x;
    int t = threadIdx.x;
    __shared__ float  st[STG];                // 16.9 KB staged det ch0-4
    __shared__ float  iou_sm[NOBJ * NANCH];   // 160
    __shared__ float4 box_sm[NOBJ];
    __shared__ int    gx_sm[NOBJ], gy_sm[NOBJ];
    __shared__ int    cls_sm[NOBJ];
    __shared__ int    flat_sm[NOBJ];
    __shared__ int    aidx_sm[NOBJ];
    __shared__ int    win_sm[NOBJ];
    __shared__ float  sm4[4][4];

    const float* detb = det + (size_t)b * (NANCH * CHUNK);

    // ---- Stage ch0-4 of each anchor (channels 0-4 are contiguous per anchor) ----
    for (int i = t; i < STG; i += 256) {
        int a = i / (5 * PLANE);
        int r = i - a * (5 * PLANE);
        st[i] = detb[(size_t)a * CHUNK + r];
    }
    // ---- GT metadata (t < 32) ----
    if (t < NOBJ) {
        float4 g = ((const float4*)gt_boxes)[b * NOBJ + t];
        box_sm[t] = g;
        gx_sm[t] = (int)floorf(g.x * 13.0f);
        gy_sm[t] = (int)floorf(g.y * 13.0f);
        cls_sm[t] = gt_class[b * NOBJ + t];
    }
    __syncthreads();

    float loss = 0.0f, objl = 0.0f, noobjl = 0.0f, confl = 0.0f;

    // ---- Phase D: baseline 0.5*d4^2 over this batch (from LDS) ----
    {
        float s = 0.0f;
        for (int i = t; i < NANCH * PLANE; i += 256) {
            int a = i / PLANE, pos = i - a * PLANE;
            float d = st[a * (5 * PLANE) + 4 * PLANE + pos];
            s += d * d;
        }
        loss += 0.5f * s;
        noobjl += 0.5f * s;
    }

    // ---- Phase A: IoU per (gt, anchor) from LDS ----
    if (t < NOBJ * NANCH) {
        int gt = t / NANCH, a = t - gt * NANCH;
        float4 g = box_sm[gt];
        float x = g.x, y = g.y, w = g.z, h = g.w;
        int gx = gx_sm[gt], gy = gy_sm[gt];
        int pos = gy * GRIDSZ + gx;
        const float* sa = st + a * (5 * PLANE);
        float px = sa[pos];
        float py = sa[PLANE + pos];
        float pw = sa[2 * PLANE + pos] * AW[a];
        float ph = sa[3 * PLANE + pos] * AH[a];
        float gx0 = x - w * 0.5f, gy0 = y - h * 0.5f;
        float gx1 = x + w * 0.5f, gy1 = y + h * 0.5f;
        float a1 = (gx1 - gx0 + 1.0f) * (gy1 - gy0 + 1.0f);
        float bx0 = (px + (float)gx) / 13.0f - pw * 0.5f;
        float by0 = (py + (float)gy) / 13.0f - ph * 0.5f;
        float bx1 = bx0 + pw, by1 = by0 + ph;
        float ix0 = fmaxf(gx0, bx0), iy0 = fmaxf(gy0, by0);
        float ix1 = fminf(gx1, bx1), iy1 = fminf(gy1, by1);
        float inter = (ix1 - ix0 + 1.0f) * (iy1 - iy0 + 1.0f);
        float a2 = (bx1 - bx0 + 1.0f) * (by1 - by0 + 1.0f);
        iou_sm[t] = inter / (a1 + a2 - inter);
    }
    __syncthreads();

    // ---- Phase B1: per-GT argmax (first-max, matches jnp.argmax) ----
    if (t < NOBJ) {
        float best = -INFINITY;
        int aidx = 0;
        #pragma unroll
        for (int a = 0; a < NANCH; ++a) {
            float v = iou_sm[t * NANCH + a];
            if (v > best) { best = v; aidx = a; }
        }
        aidx_sm[t] = aidx;
        flat_sm[t] = (aidx * GRIDSZ + gy_sm[t]) * GRIDSZ + gx_sm[t];  // batch-local slot
    }
    __syncthreads();

    // ---- Phase B2: winner = no higher-index GT in batch with same slot ----
    if (t < NOBJ) {
        int f = flat_sm[t];
        int winner = 1;
        for (int m = t + 1; m < NOBJ; ++m)
            if (flat_sm[m] == f) winner = 0;
        win_sm[t] = winner;
    }
    __syncthreads();

    // ---- Phase C1: ch0-4 terms + baseline subtraction (winners, from LDS) ----
    if (t < NOBJ && win_sm[t]) {
        int aidx = aidx_sm[t];
        int gx = gx_sm[t], gy = gy_sm[t];
        int pos = gy * GRIDSZ + gx;
        const float* sa = st + aidx * (5 * PLANE);
        float px = sa[pos];
        float py = sa[PLANE + pos];
        float pw = sa[2 * PLANE + pos] * AW[aidx];
        float ph = sa[3 * PLANE + pos] * AH[aidx];
        float d4 = sa[4 * PLANE + pos];
        float4 g = box_sm[t];
        float tx = g.x * 13.0f - (float)gx;
        float ty = g.y * 13.0f - (float)gy;
        float e, tt, corr = 0.0f;
        e = tx - px;   tt = 5.0f * e * e; corr += tt; objl += tt;
        e = ty - py;   tt = 5.0f * e * e; corr += tt; objl += tt;
        e = g.z - pw;  tt = 5.0f * e * e; corr += tt; objl += tt;
        e = g.w - ph;  tt = 5.0f * e * e; corr += tt; objl += tt;
        e = 1.0f - d4; tt = e * e;        corr += tt; objl += tt;
        float sub = 0.5f * d4 * d4;   // baseline term this owned cell replaces
        loss += corr - sub;
        noobjl -= sub;
    }

    // ---- Phase C2: class-channel terms, 640 (gt, c) items over 256 threads ----
    for (int item = t; item < NOBJ * 20; item += 256) {
        int gt = item / 20;
        int c = 5 + (item - gt * 20);
        if (win_sm[gt]) {
            int aidx = aidx_sm[gt];
            float d = detb[((size_t)aidx * NCHAN + c) * PLANE + gy_sm[gt] * GRIDSZ + gx_sm[gt]];
            float gtv = (c - 5 == cls_sm[gt]) ? 1.0f : 0.0f;
            float e = gtv - d;
            float tt = e * e;
            loss += tt;
            confl += tt;
        }
    }

    // ---- block reduction -> one float4 partial ----
    #pragma unroll
    for (int off = 32; off > 0; off >>= 1) {
        loss   += __shfl_down(loss, off);
        objl   += __shfl_down(objl, off);
        noobjl += __shfl_down(noobjl, off);
        confl  += __shfl_down(confl, off);
    }
    int lane = t & 63;
    int wid  = t >> 6;
    if (lane == 0) {
        sm4[wid][0] = loss; sm4[wid][1] = objl; sm4[wid][2] = noobjl; sm4[wid][3] = confl;
    }
    __syncthreads();
    if (t == 0) {
        float s0 = 0, s1 = 0, s2 = 0, s3 = 0;
        #pragma unroll
        for (int i = 0; i < 4; ++i) {
            s0 += sm4[i][0]; s1 += sm4[i][1]; s2 += sm4[i][2]; s3 += sm4[i][3];
        }
        partials[blockIdx.x] = make_float4(s0, s1, s2, s3);
    }
}

// Final: one block sums BATCH float4 partials and writes out[0..3].
__global__ void reduce_kernel(const float4* __restrict__ partials,
                              float* __restrict__ out) {
    float s0 = 0, s1 = 0, s2 = 0, s3 = 0;
    for (int i = threadIdx.x; i < BATCH; i += 256) {
        float4 v = partials[i];
        s0 += v.x; s1 += v.y; s2 += v.z; s3 += v.w;
    }
    #pragma unroll
    for (int off = 32; off > 0; off >>= 1) {
        s0 += __shfl_down(s0, off);
        s1 += __shfl_down(s1, off);
        s2 += __shfl_down(s2, off);
        s3 += __shfl_down(s3, off);
    }
    __shared__ float sm[4][4];
    int lane = threadIdx.x & 63;
    int wid  = threadIdx.x >> 6;
    if (lane == 0) {
        sm[wid][0] = s0; sm[wid][1] = s1; sm[wid][2] = s2; sm[wid][3] = s3;
    }
    __syncthreads();
    if (threadIdx.x == 0) {
        float a0 = 0, a1 = 0, a2 = 0, a3 = 0;
        #pragma unroll
        for (int i = 0; i < 4; ++i) {
            a0 += sm[i][0]; a1 += sm[i][1]; a2 += sm[i][2]; a3 += sm[i][3];
        }
        out[0] = a0; out[1] = a1; out[2] = a2; out[3] = a3;
    }
}

extern "C" void kernel_launch(void* const* d_in, const int* in_sizes, int n_in,
                              void* d_out, int out_size, void* d_ws, size_t ws_size,
                              hipStream_t stream) {
    const float* det = (const float*)d_in[0];
    const float* gtb = (const float*)d_in[1];
    const int*   gtc = (const int*)d_in[2];
    float* out = (float*)d_out;
    float4* partials = (float4*)d_ws;   // BATCH * 16 B = 32 KB

    main_kernel<<<BATCH, 256, 0, stream>>>(det, gtb, gtc, partials);
    reduce_kernel<<<1, 256, 0, stream>>>(partials, out);
}